// Round 3
// baseline (210.141 us; speedup 1.0000x reference)
//
#include <hip/hip_runtime.h>
#include <math.h>

// ===========================================================================
// CrossAttentionLayer — collapsed attention + bf16-MFMA SwiGLU FF.
//
// kv is broadcast over j => softmax exactly uniform => attention out = v_row,
// independent of q (Wq unused):
//   attn_out[b,c] = sum_i vrow[b, i&63] * Wout[i,c],
//   vrow[b,:] = (LN(extra[b]) @ Wkv)[64:128].
// Per position: x = LN_C(cnn); h = x@W1; ff = (silu(h[512:])*h[:512])@W2;
//   out[b,c,p] = attn_out[b,c] + ff[p,c]
//
// Round-3 structure: swapped-operand GEMM1 (mfma(W,X) -> lane holds 4
// consecutive FFI per position -> cvt_pk_bf16 pack, conflict-free b64 val
// writes), additive chunk swizzle phys=(chunk+row)&MASK for all LDS tiles,
// b128 xs staging writes, software-pipelined GEMM1(kc+1)/GEMM2(kc) phases.
// ===========================================================================

#define BATCH 16
#define CDIM  256
#define HW    4096

using short8 = __attribute__((ext_vector_type(8))) short;
using f32x4  = __attribute__((ext_vector_type(4))) float;
using u32x2  = __attribute__((ext_vector_type(2))) unsigned int;
using u32x4  = __attribute__((ext_vector_type(4))) unsigned int;
typedef unsigned int   u32;
typedef unsigned short u16;

__device__ __forceinline__ u16 f2bf(float f) {
    u32 u = __float_as_uint(f);
    u += 0x7fffu + ((u >> 16) & 1u);   // round-nearest-even
    return (u16)(u >> 16);
}

__device__ __forceinline__ u32 cvtpk_bf16(float lo, float hi) {
    u32 r;
    asm("v_cvt_pk_bf16_f32 %0, %1, %2" : "=v"(r) : "v"(lo), "v"(hi));
    return r;
}

// ---------------------------------------------------------------------------
// Prep: blocks 0..15  -> collapsed attention rows (16 x 256 f32)
//       blocks 16..79 -> W1 (256x1024) -> W1^T bf16 (1024x256)
//       blocks 80..111-> W2 (512x256)  -> W2^T bf16 (256x512)
// ---------------------------------------------------------------------------
__global__ void prep_kernel(const float* __restrict__ extra,
                            const float* __restrict__ ln2_g,
                            const float* __restrict__ ln2_b,
                            const float* __restrict__ Wkv,
                            const float* __restrict__ Wout,
                            const float* __restrict__ W1,
                            const float* __restrict__ W2,
                            float* __restrict__ attn_out,
                            u16* __restrict__ w1t,
                            u16* __restrict__ w2t)
{
    const int t = threadIdx.x;
    if (blockIdx.x < BATCH) {
        __shared__ float e[512];
        __shared__ float red[256], red2[256];
        __shared__ float vpart[256];
        __shared__ float vrow[64];
        const int b = blockIdx.x;
        float a0 = extra[b * 512 + t];
        float a1 = extra[b * 512 + 256 + t];
        e[t] = a0; e[t + 256] = a1;
        red[t] = a0 + a1; red2[t] = a0 * a0 + a1 * a1;
        __syncthreads();
        for (int off = 128; off; off >>= 1) {
            if (t < off) { red[t] += red[t + off]; red2[t] += red2[t + off]; }
            __syncthreads();
        }
        const float mean = red[0] * (1.0f / 512.0f);
        const float var  = red2[0] * (1.0f / 512.0f) - mean * mean;
        const float rs   = rsqrtf(var + 1e-5f);
        e[t]       = (e[t]       - mean) * rs * ln2_g[t]       + ln2_b[t];
        e[t + 256] = (e[t + 256] - mean) * rs * ln2_g[t + 256] + ln2_b[t + 256];
        __syncthreads();
        {   // vrow[d] = sum_i e[i]*Wkv[i,64+d], split over 4 i-parts
            const int d = t & 63, part = t >> 6;
            float acc = 0.0f;
            for (int i = part * 128; i < part * 128 + 128; ++i)
                acc += e[i] * Wkv[i * 128 + 64 + d];
            vpart[t] = acc;
        }
        __syncthreads();
        if (t < 64) vrow[t] = vpart[t] + vpart[t + 64] + vpart[t + 128] + vpart[t + 192];
        __syncthreads();
        float acc = 0.0f;
        for (int i = 0; i < 512; ++i) acc += vrow[i & 63] * Wout[i * 256 + t];
        attn_out[b * 256 + t] = acc;
    } else {
        __shared__ float tile[64][65];   // +1 pad: conflict-free transposed read
        int id = blockIdx.x - BATCH;
        const float* src; u16* dst; int Rr, Cc, tr, tc;
        if (id < 64) { src = W1; dst = w1t; Rr = 256; Cc = 1024; tr = id >> 4; tc = id & 15; }
        else { id -= 64; src = W2; dst = w2t; Rr = 512; Cc = 256; tr = id >> 2; tc = id & 3; }
        const int rl = t >> 6, col = t & 63;
#pragma unroll
        for (int i = 0; i < 16; ++i) {
            int r = i * 4 + rl;
            tile[r][col] = src[(size_t)(tr * 64 + r) * Cc + tc * 64 + col];
        }
        __syncthreads();
#pragma unroll
        for (int i = 0; i < 16; ++i) {
            int n = i * 4 + rl;
            dst[(size_t)(tc * 64 + n) * Rr + tr * 64 + col] = f2bf(tile[col][n]);
        }
    }
}

// ---------------------------------------------------------------------------
// Main: 64 positions per block (1024 blocks), 4 waves, 3 blocks/CU.
// LDS: xs 64x256 bf16 (32 KiB), val 64x128 bf16 (16 KiB, overlaid with red).
// Swizzle: 16B-chunk phys = (logicalChunk + row) & (chunksPerRow-1).
// ---------------------------------------------------------------------------
__global__ void __launch_bounds__(256, 3) main_kernel(
    const float* __restrict__ cnn,      // (16,256,64,64)
    const float* __restrict__ ln1_g,
    const float* __restrict__ ln1_b,
    const u16*  __restrict__ w1t,       // (1024,256) bf16: row n, col c
    const u16*  __restrict__ w2t,       // (256,512)  bf16: row c, col k
    const float* __restrict__ attn_out, // (16,256)
    float* __restrict__ out)            // (16,256,64,64)
{
    __shared__ u16 xs[64 * 256];   // 32 KiB
    __shared__ u16 val[64 * 128];  // 16 KiB (first 2.5 KiB doubles as red[])
    float* red = (float*)val;

    const int t  = threadIdx.x;
    const int b  = blockIdx.x >> 6;
    const int p0 = (blockIdx.x & 63) << 6;
    const int p  = t & 63;
    const int q  = t >> 6;          // wave id
    const int l15 = p & 15;
    const int lg  = p >> 4;

    // ---- load cnn (coalesced along p) + LN stats ----
    const float* cb = cnn + (size_t)b * CDIM * HW + p0 + p;
    float v[64];
    float s = 0.0f, s2 = 0.0f;
#pragma unroll
    for (int i = 0; i < 64; ++i) {
        float x = cb[(size_t)(q * 64 + i) * HW];
        v[i] = x; s += x; s2 += x * x;
    }
    red[q * 64 + p] = s;
    red[256 + q * 64 + p] = s2;
    __syncthreads();
    if (t < 64) {
        float ss = red[t] + red[64 + t] + red[128 + t] + red[192 + t];
        float sq = red[256 + t] + red[320 + t] + red[384 + t] + red[448 + t];
        float mean = ss * (1.0f / 256.0f);
        float var  = sq * (1.0f / 256.0f) - mean * mean;
        red[512 + t] = mean;
        red[576 + t] = rsqrtf(var + 1e-5f);
    }
    __syncthreads();
    {
        const float mean = red[512 + p], rs = red[576 + p];
#pragma unroll
        for (int ic = 0; ic < 8; ++ic) {
            u32x4 w;
#pragma unroll
            for (int e2 = 0; e2 < 4; ++e2) {
                int c = q * 64 + ic * 8 + e2 * 2;
                float x0 = (v[ic * 8 + e2 * 2]     - mean) * rs * ln1_g[c]     + ln1_b[c];
                float x1 = (v[ic * 8 + e2 * 2 + 1] - mean) * rs * ln1_g[c + 1] + ln1_b[c + 1];
                w[e2] = cvtpk_bf16(x0, x1);
            }
            int phys = ((q * 8 + ic) + p) & 31;
            *(u32x4*)((char*)xs + p * 512 + phys * 16) = w;   // b128, conflict-free
        }
    }
    __syncthreads();   // xs ready; red reads all complete (val now writable)

    f32x4 acc2[4][4];
#pragma unroll
    for (int n = 0; n < 4; ++n)
#pragma unroll
        for (int m = 0; m < 4; ++m)
            acc2[n][m] = (f32x4){0.0f, 0.0f, 0.0f, 0.0f};

    u32 pk[2][4][2];   // packed silu output: [n][m][pair]  (16 u32)

    // GEMM1(kc): swapped operands mfma(W, X) -> lane l15 = position,
    // regs (lg*4+j) = FFI. silu folded in; result kept packed in pk.
#define GEMM1(kc_) do {                                                          \
        const int nb = (kc_) * 128 + q * 32;                                     \
        _Pragma("unroll")                                                        \
        for (int n = 0; n < 2; ++n) {                                            \
            f32x4 axh[4], ag[4];                                                 \
            _Pragma("unroll")                                                    \
            for (int m = 0; m < 4; ++m) {                                        \
                axh[m] = (f32x4){0.0f, 0.0f, 0.0f, 0.0f};                        \
                ag[m]  = (f32x4){0.0f, 0.0f, 0.0f, 0.0f};                        \
            }                                                                    \
            _Pragma("unroll")                                                    \
            for (int ks = 0; ks < 8; ++ks) {                                     \
                short8 a_[4];                                                    \
                _Pragma("unroll")                                                \
                for (int m = 0; m < 4; ++m) {                                    \
                    int row = m * 16 + l15;                                      \
                    int ph  = ((ks * 4 + lg) + row) & 31;                        \
                    a_[m] = *(const short8*)((const char*)xs + row * 512 + ph * 16); \
                }                                                                \
                short8 bx = *(const short8*)(w1t + (size_t)(nb + n * 16 + l15) * 256 + ks * 32 + lg * 8);       \
                short8 bg = *(const short8*)(w1t + (size_t)(512 + nb + n * 16 + l15) * 256 + ks * 32 + lg * 8); \
                _Pragma("unroll")                                                \
                for (int m = 0; m < 4; ++m) {                                    \
                    axh[m] = __builtin_amdgcn_mfma_f32_16x16x32_bf16(bx, a_[m], axh[m], 0, 0, 0); \
                    ag[m]  = __builtin_amdgcn_mfma_f32_16x16x32_bf16(bg, a_[m], ag[m], 0, 0, 0);  \
                }                                                                \
            }                                                                    \
            _Pragma("unroll")                                                    \
            for (int m = 0; m < 4; ++m) {                                        \
                float sv[4];                                                     \
                _Pragma("unroll")                                                \
                for (int j = 0; j < 4; ++j) {                                    \
                    float g = ag[m][j];                                          \
                    float e = __expf(-g);                                        \
                    sv[j] = axh[m][j] * g * __builtin_amdgcn_rcpf(1.0f + e);     \
                }                                                                \
                pk[n][m][0] = cvtpk_bf16(sv[0], sv[1]);                          \
                pk[n][m][1] = cvtpk_bf16(sv[2], sv[3]);                          \
            }                                                                    \
        }                                                                        \
    } while (0)

    // conflict-free b64 val writes (4 consecutive k per thread)
#define VALWRITE() do {                                                          \
        _Pragma("unroll")                                                        \
        for (int n = 0; n < 2; ++n)                                              \
        _Pragma("unroll")                                                        \
        for (int m = 0; m < 4; ++m) {                                            \
            int row = m * 16 + l15;                                              \
            int k0  = q * 32 + n * 16 + lg * 4;                                  \
            int ph  = ((k0 >> 3) + row) & 15;                                    \
            *(u32x2*)((char*)val + row * 256 + ph * 16 + (lg & 1) * 8) =         \
                (u32x2){pk[n][m][0], pk[n][m][1]};                               \
        }                                                                        \
    } while (0)

#define GEMM2(kc_) do {                                                          \
        _Pragma("unroll")                                                        \
        for (int ks = 0; ks < 4; ++ks) {                                         \
            short8 a2[4], b2[4];                                                 \
            _Pragma("unroll")                                                    \
            for (int m = 0; m < 4; ++m) {                                        \
                int row = m * 16 + l15;                                          \
                int ph  = ((ks * 4 + lg) + row) & 15;                            \
                a2[m] = *(const short8*)((const char*)val + row * 256 + ph * 16);\
            }                                                                    \
            _Pragma("unroll")                                                    \
            for (int n = 0; n < 4; ++n)                                          \
                b2[n] = *(const short8*)(w2t + (size_t)(q * 64 + n * 16 + l15) * 512 + (kc_) * 128 + ks * 32 + lg * 8); \
            _Pragma("unroll")                                                    \
            for (int n = 0; n < 4; ++n)                                          \
            _Pragma("unroll")                                                    \
            for (int m = 0; m < 4; ++m)                                          \
                acc2[n][m] = __builtin_amdgcn_mfma_f32_16x16x32_bf16(a2[m], b2[n], acc2[n][m], 0, 0, 0); \
        }                                                                        \
    } while (0)

    GEMM1(0);
    VALWRITE();
    __syncthreads();
#pragma unroll
    for (int kc = 0; kc < 4; ++kc) {
        if (kc < 3) GEMM1(kc + 1);   // next chunk's GEMM1+silu (regs only)
        GEMM2(kc);                   // current chunk's GEMM2 (reads val)
        if (kc < 3) {
            __syncthreads();         // all waves done reading val(kc)
            VALWRITE();
            __syncthreads();         // val(kc+1) visible
        }
    }

    // ---- epilogue: + attn row, f32x4 stores (4 consecutive positions) ----
    float att[4];
#pragma unroll
    for (int n = 0; n < 4; ++n) att[n] = attn_out[b * 256 + q * 64 + n * 16 + l15];
    float* ob = out + (size_t)b * CDIM * HW;
#pragma unroll
    for (int n = 0; n < 4; ++n) {
        int c = q * 64 + n * 16 + l15;
#pragma unroll
        for (int m = 0; m < 4; ++m) {
            f32x4 r = acc2[n][m];
            r[0] += att[n]; r[1] += att[n]; r[2] += att[n]; r[3] += att[n];
            *(f32x4*)(ob + (size_t)c * HW + p0 + m * 16 + lg * 4) = r;
        }
    }
#undef GEMM1
#undef GEMM2
#undef VALWRITE
}

// ---------------------------------------------------------------------------
extern "C" void kernel_launch(void* const* d_in, const int* in_sizes, int n_in,
                              void* d_out, int out_size, void* d_ws, size_t ws_size,
                              hipStream_t stream) {
    const float* cnn   = (const float*)d_in[0];
    const float* extra = (const float*)d_in[1];
    const float* ln1_g = (const float*)d_in[2];
    const float* ln1_b = (const float*)d_in[3];
    const float* ln2_g = (const float*)d_in[4];
    const float* ln2_b = (const float*)d_in[5];
    // d_in[6] = Wq — provably unused
    const float* Wkv   = (const float*)d_in[7];
    const float* Wout  = (const float*)d_in[8];
    const float* W1    = (const float*)d_in[9];
    const float* W2    = (const float*)d_in[10];
    float* out = (float*)d_out;

    char* ws = (char*)d_ws;
    float* attn_out = (float*)ws;                          // 16 KiB
    u16*   w1t      = (u16*)(ws + 16 * 1024);              // 512 KiB
    u16*   w2t      = (u16*)(ws + 16 * 1024 + 512 * 1024); // 256 KiB

    prep_kernel<<<112, 256, 0, stream>>>(extra, ln2_g, ln2_b, Wkv, Wout, W1, W2,
                                         attn_out, w1t, w2t);
    main_kernel<<<BATCH * 64, 256, 0, stream>>>(cnn, ln1_g, ln1_b, w1t, w2t,
                                                attn_out, out);
}

// Round 4
// 163.675 us; speedup vs baseline: 1.2839x; 1.2839x over previous
//
#include <hip/hip_runtime.h>
#include <math.h>

// ===========================================================================
// CrossAttentionLayer — collapsed attention + bf16-MFMA SwiGLU FF.
//
// kv is broadcast over j => softmax exactly uniform => attention out = v_row,
// independent of q (Wq unused):
//   attn_out[b,c] = sum_i vrow[b, i&63] * Wout[i,c],
//   vrow[b,:] = (LN(extra[b]) @ Wkv)[64:128].
// Per position: x = LN_C(cnn); h = x@W1; ff = (silu(h[512:])*h[:512])@W2;
//   out[b,c,p] = attn_out[b,c] + ff[p,c]
//
// Round-4: XOR chunk swizzle phys = chunk ^ (row&7) on ALL LDS tiles
// (conflict-free for b128 writes, fragment reads, and u32x2 val writes —
// additive swizzle was 4-way conflicted), swapped-operand GEMM1
// (mfma(W,X) -> lane holds 4 consecutive FFI per position -> cvt_pk pack,
// 8B val writes), NO software pipeline / NO min-occupancy bound (round-3
// spilled: +225MB scratch traffic from launch_bounds(256,3) reg cap).
// ===========================================================================

#define BATCH 16
#define CDIM  256
#define HW    4096

using short8 = __attribute__((ext_vector_type(8))) short;
using f32x4  = __attribute__((ext_vector_type(4))) float;
using u32x2  = __attribute__((ext_vector_type(2))) unsigned int;
using u32x4  = __attribute__((ext_vector_type(4))) unsigned int;
typedef unsigned int   u32;
typedef unsigned short u16;

__device__ __forceinline__ u16 f2bf(float f) {
    u32 u = __float_as_uint(f);
    u += 0x7fffu + ((u >> 16) & 1u);   // round-nearest-even
    return (u16)(u >> 16);
}

__device__ __forceinline__ u32 cvtpk_bf16(float lo, float hi) {
    u32 r;
    asm("v_cvt_pk_bf16_f32 %0, %1, %2" : "=v"(r) : "v"(lo), "v"(hi));
    return r;
}

// ---------------------------------------------------------------------------
// Prep: blocks 0..15  -> collapsed attention rows (16 x 256 f32)
//       blocks 16..79 -> W1 (256x1024) -> W1^T bf16 (1024x256)
//       blocks 80..111-> W2 (512x256)  -> W2^T bf16 (256x512)
// ---------------------------------------------------------------------------
__global__ void prep_kernel(const float* __restrict__ extra,
                            const float* __restrict__ ln2_g,
                            const float* __restrict__ ln2_b,
                            const float* __restrict__ Wkv,
                            const float* __restrict__ Wout,
                            const float* __restrict__ W1,
                            const float* __restrict__ W2,
                            float* __restrict__ attn_out,
                            u16* __restrict__ w1t,
                            u16* __restrict__ w2t)
{
    const int t = threadIdx.x;
    if (blockIdx.x < BATCH) {
        __shared__ float e[512];
        __shared__ float red[256], red2[256];
        __shared__ float vpart[256];
        __shared__ float vrow[64];
        const int b = blockIdx.x;
        float a0 = extra[b * 512 + t];
        float a1 = extra[b * 512 + 256 + t];
        e[t] = a0; e[t + 256] = a1;
        red[t] = a0 + a1; red2[t] = a0 * a0 + a1 * a1;
        __syncthreads();
        for (int off = 128; off; off >>= 1) {
            if (t < off) { red[t] += red[t + off]; red2[t] += red2[t + off]; }
            __syncthreads();
        }
        const float mean = red[0] * (1.0f / 512.0f);
        const float var  = red2[0] * (1.0f / 512.0f) - mean * mean;
        const float rs   = rsqrtf(var + 1e-5f);
        e[t]       = (e[t]       - mean) * rs * ln2_g[t]       + ln2_b[t];
        e[t + 256] = (e[t + 256] - mean) * rs * ln2_g[t + 256] + ln2_b[t + 256];
        __syncthreads();
        {   // vrow[d] = sum_i e[i]*Wkv[i,64+d], split over 4 i-parts
            const int d = t & 63, part = t >> 6;
            float acc = 0.0f;
            for (int i = part * 128; i < part * 128 + 128; ++i)
                acc += e[i] * Wkv[i * 128 + 64 + d];
            vpart[t] = acc;
        }
        __syncthreads();
        if (t < 64) vrow[t] = vpart[t] + vpart[t + 64] + vpart[t + 128] + vpart[t + 192];
        __syncthreads();
        {   // 4-way ILP on the dependent FMA chain
            float a0_ = 0.f, a1_ = 0.f, a2_ = 0.f, a3_ = 0.f;
            for (int i = 0; i < 512; i += 4) {
                a0_ += vrow[i & 63]       * Wout[(i)     * 256 + t];
                a1_ += vrow[(i + 1) & 63] * Wout[(i + 1) * 256 + t];
                a2_ += vrow[(i + 2) & 63] * Wout[(i + 2) * 256 + t];
                a3_ += vrow[(i + 3) & 63] * Wout[(i + 3) * 256 + t];
            }
            attn_out[b * 256 + t] = (a0_ + a1_) + (a2_ + a3_);
        }
    } else {
        __shared__ float tile[64][65];   // +1 pad: conflict-free transposed read
        int id = blockIdx.x - BATCH;
        const float* src; u16* dst; int Rr, Cc, tr, tc;
        if (id < 64) { src = W1; dst = w1t; Rr = 256; Cc = 1024; tr = id >> 4; tc = id & 15; }
        else { id -= 64; src = W2; dst = w2t; Rr = 512; Cc = 256; tr = id >> 2; tc = id & 3; }
        const int rl = t >> 6, col = t & 63;
#pragma unroll
        for (int i = 0; i < 16; ++i) {
            int r = i * 4 + rl;
            tile[r][col] = src[(size_t)(tr * 64 + r) * Cc + tc * 64 + col];
        }
        __syncthreads();
#pragma unroll
        for (int i = 0; i < 16; ++i) {
            int n = i * 4 + rl;
            dst[(size_t)(tc * 64 + n) * Rr + tr * 64 + col] = f2bf(tile[col][n]);
        }
    }
}

// ---------------------------------------------------------------------------
// Main: 64 positions per block (1024 blocks), 4 waves.
// LDS: xs 64x256 bf16 (32 KiB), val 64x128 bf16 (16 KiB, overlaid with red).
// Swizzle: 16B-chunk phys = logicalChunk ^ (row & 7)  (XOR — conflict-free).
// ---------------------------------------------------------------------------
__global__ void __launch_bounds__(256) main_kernel(
    const float* __restrict__ cnn,      // (16,256,64,64)
    const float* __restrict__ ln1_g,
    const float* __restrict__ ln1_b,
    const u16*  __restrict__ w1t,       // (1024,256) bf16: row n, col c
    const u16*  __restrict__ w2t,       // (256,512)  bf16: row c, col k
    const float* __restrict__ attn_out, // (16,256)
    float* __restrict__ out)            // (16,256,64,64)
{
    __shared__ u16 xs[64 * 256];   // 32 KiB
    __shared__ u16 val[64 * 128];  // 16 KiB (first 2.5 KiB doubles as red[])
    float* red = (float*)val;

    const int t  = threadIdx.x;
    const int b  = blockIdx.x >> 6;
    const int p0 = (blockIdx.x & 63) << 6;
    const int p  = t & 63;
    const int q  = t >> 6;          // wave id
    const int l15 = p & 15;
    const int lg  = p >> 4;

    // ---- load cnn (coalesced along p) + LN stats ----
    const float* cb = cnn + (size_t)b * CDIM * HW + p0 + p;
    float v[64];
    float s = 0.0f, s2 = 0.0f;
#pragma unroll
    for (int i = 0; i < 64; ++i) {
        float x = cb[(size_t)(q * 64 + i) * HW];
        v[i] = x; s += x; s2 += x * x;
    }
    red[q * 64 + p] = s;
    red[256 + q * 64 + p] = s2;
    __syncthreads();
    if (t < 64) {
        float ss = red[t] + red[64 + t] + red[128 + t] + red[192 + t];
        float sq = red[256 + t] + red[320 + t] + red[384 + t] + red[448 + t];
        float mean = ss * (1.0f / 256.0f);
        float var  = sq * (1.0f / 256.0f) - mean * mean;
        red[512 + t] = mean;
        red[576 + t] = rsqrtf(var + 1e-5f);
    }
    __syncthreads();
    {   // normalize + bf16 pack + XOR-swizzled b128 LDS writes
        const float mean = red[512 + p], rs = red[576 + p];
#pragma unroll
        for (int ic = 0; ic < 8; ++ic) {
            u32x4 w;
#pragma unroll
            for (int e2 = 0; e2 < 4; ++e2) {
                int c = q * 64 + ic * 8 + e2 * 2;
                float x0 = (v[ic * 8 + e2 * 2]     - mean) * rs * ln1_g[c]     + ln1_b[c];
                float x1 = (v[ic * 8 + e2 * 2 + 1] - mean) * rs * ln1_g[c + 1] + ln1_b[c + 1];
                w[e2] = cvtpk_bf16(x0, x1);
            }
            int phys = (q * 8 + ic) ^ (p & 7);
            *(u32x4*)((char*)xs + p * 512 + phys * 16) = w;   // conflict-free
        }
    }
    __syncthreads();   // xs ready; all red reads done (val now writable)

    f32x4 acc2[4][4];
#pragma unroll
    for (int n = 0; n < 4; ++n)
#pragma unroll
        for (int m = 0; m < 4; ++m)
            acc2[n][m] = (f32x4){0.0f, 0.0f, 0.0f, 0.0f};

    u32 pk[2][4][2];   // packed silu output: [n][m][pair]

    // GEMM1(kc): swapped operands mfma(W, X) -> D col (l15) = position,
    // D rows (lg*4+j) = FFI. silu folded; result packed into pk.
#define GEMM1(kc_) do {                                                          \
        const int nb = (kc_) * 128 + q * 32;                                     \
        f32x4 axh[2][4], ag[2][4];                                               \
        _Pragma("unroll")                                                        \
        for (int n = 0; n < 2; ++n)                                              \
        _Pragma("unroll")                                                        \
        for (int m = 0; m < 4; ++m) {                                            \
            axh[n][m] = (f32x4){0.0f, 0.0f, 0.0f, 0.0f};                         \
            ag[n][m]  = (f32x4){0.0f, 0.0f, 0.0f, 0.0f};                         \
        }                                                                        \
        _Pragma("unroll")                                                        \
        for (int ks = 0; ks < 8; ++ks) {                                         \
            short8 a_[4];                                                        \
            _Pragma("unroll")                                                    \
            for (int m = 0; m < 4; ++m) {                                        \
                int row = m * 16 + l15;                                          \
                int ph  = (ks * 4 + lg) ^ (row & 7);                             \
                a_[m] = *(const short8*)((const char*)xs + row * 512 + ph * 16); \
            }                                                                    \
            short8 bx[2], bg[2];                                                 \
            _Pragma("unroll")                                                    \
            for (int n = 0; n < 2; ++n) {                                        \
                bx[n] = *(const short8*)(w1t + (size_t)(nb + n * 16 + l15) * 256 + ks * 32 + lg * 8);       \
                bg[n] = *(const short8*)(w1t + (size_t)(512 + nb + n * 16 + l15) * 256 + ks * 32 + lg * 8); \
            }                                                                    \
            _Pragma("unroll")                                                    \
            for (int n = 0; n < 2; ++n)                                          \
            _Pragma("unroll")                                                    \
            for (int m = 0; m < 4; ++m) {                                        \
                axh[n][m] = __builtin_amdgcn_mfma_f32_16x16x32_bf16(bx[n], a_[m], axh[n][m], 0, 0, 0); \
                ag[n][m]  = __builtin_amdgcn_mfma_f32_16x16x32_bf16(bg[n], a_[m], ag[n][m], 0, 0, 0);  \
            }                                                                    \
        }                                                                        \
        _Pragma("unroll")                                                        \
        for (int n = 0; n < 2; ++n)                                              \
        _Pragma("unroll")                                                        \
        for (int m = 0; m < 4; ++m) {                                            \
            float sv[4];                                                         \
            _Pragma("unroll")                                                    \
            for (int j = 0; j < 4; ++j) {                                        \
                float g = ag[n][m][j];                                           \
                sv[j] = axh[n][m][j] * g * __builtin_amdgcn_rcpf(1.0f + __expf(-g)); \
            }                                                                    \
            pk[n][m][0] = cvtpk_bf16(sv[0], sv[1]);                              \
            pk[n][m][1] = cvtpk_bf16(sv[2], sv[3]);                              \
        }                                                                        \
    } while (0)

    // conflict-free 8B val writes (4 consecutive k per lane)
#define VALWRITE() do {                                                          \
        _Pragma("unroll")                                                        \
        for (int n = 0; n < 2; ++n)                                              \
        _Pragma("unroll")                                                        \
        for (int m = 0; m < 4; ++m) {                                            \
            int row = m * 16 + l15;                                              \
            int lc  = q * 4 + n * 2 + (lg >> 1);          /* logical chunk */    \
            int ph  = lc ^ (row & 7);                                            \
            *(u32x2*)((char*)val + row * 256 + ph * 16 + (lg & 1) * 8) =         \
                (u32x2){pk[n][m][0], pk[n][m][1]};                               \
        }                                                                        \
    } while (0)

#define GEMM2(kc_) do {                                                          \
        _Pragma("unroll")                                                        \
        for (int ks = 0; ks < 4; ++ks) {                                         \
            short8 a2[4], b2[4];                                                 \
            _Pragma("unroll")                                                    \
            for (int m = 0; m < 4; ++m) {                                        \
                int row = m * 16 + l15;                                          \
                int ph  = (ks * 4 + lg) ^ (row & 7);                             \
                a2[m] = *(const short8*)((const char*)val + row * 256 + ph * 16);\
            }                                                                    \
            _Pragma("unroll")                                                    \
            for (int n = 0; n < 4; ++n)                                          \
                b2[n] = *(const short8*)(w2t + (size_t)(q * 64 + n * 16 + l15) * 512 + (kc_) * 128 + ks * 32 + lg * 8); \
            _Pragma("unroll")                                                    \
            for (int n = 0; n < 4; ++n)                                          \
            _Pragma("unroll")                                                    \
            for (int m = 0; m < 4; ++m)                                          \
                acc2[n][m] = __builtin_amdgcn_mfma_f32_16x16x32_bf16(a2[m], b2[n], acc2[n][m], 0, 0, 0); \
        }                                                                        \
    } while (0)

    GEMM1(0);
    VALWRITE();
    __syncthreads();
#pragma unroll
    for (int kc = 0; kc < 4; ++kc) {
        GEMM2(kc);
        if (kc < 3) {
            GEMM1(kc + 1);       // regs only; no val access
            __syncthreads();     // all waves done reading val(kc)
            VALWRITE();
            __syncthreads();     // val(kc+1) visible
        }
    }

    // ---- epilogue: + attn row, f32x4 stores (4 consecutive positions) ----
    float att[4];
#pragma unroll
    for (int n = 0; n < 4; ++n) att[n] = attn_out[b * 256 + q * 64 + n * 16 + l15];
    float* ob = out + (size_t)b * CDIM * HW;
#pragma unroll
    for (int n = 0; n < 4; ++n) {
        int c = q * 64 + n * 16 + l15;
#pragma unroll
        for (int m = 0; m < 4; ++m) {
            f32x4 r = acc2[n][m];
            r[0] += att[n]; r[1] += att[n]; r[2] += att[n]; r[3] += att[n];
            *(f32x4*)(ob + (size_t)c * HW + p0 + m * 16 + lg * 4) = r;
        }
    }
#undef GEMM1
#undef GEMM2
#undef VALWRITE
}

// ---------------------------------------------------------------------------
extern "C" void kernel_launch(void* const* d_in, const int* in_sizes, int n_in,
                              void* d_out, int out_size, void* d_ws, size_t ws_size,
                              hipStream_t stream) {
    const float* cnn   = (const float*)d_in[0];
    const float* extra = (const float*)d_in[1];
    const float* ln1_g = (const float*)d_in[2];
    const float* ln1_b = (const float*)d_in[3];
    const float* ln2_g = (const float*)d_in[4];
    const float* ln2_b = (const float*)d_in[5];
    // d_in[6] = Wq — provably unused
    const float* Wkv   = (const float*)d_in[7];
    const float* Wout  = (const float*)d_in[8];
    const float* W1    = (const float*)d_in[9];
    const float* W2    = (const float*)d_in[10];
    float* out = (float*)d_out;

    char* ws = (char*)d_ws;
    float* attn_out = (float*)ws;                          // 16 KiB
    u16*   w1t      = (u16*)(ws + 16 * 1024);              // 512 KiB
    u16*   w2t      = (u16*)(ws + 16 * 1024 + 512 * 1024); // 256 KiB

    prep_kernel<<<112, 256, 0, stream>>>(extra, ln2_g, ln2_b, Wkv, Wout, W1, W2,
                                         attn_out, w1t, w2t);
    main_kernel<<<BATCH * 64, 256, 0, stream>>>(cnn, ln1_g, ln1_b, w1t, w2t,
                                                attn_out, out);
}

// Round 5
// 143.659 us; speedup vs baseline: 1.4628x; 1.1393x over previous
//
#include <hip/hip_runtime.h>
#include <math.h>

// ===========================================================================
// CrossAttentionLayer — collapsed attention + bf16-MFMA SwiGLU FF.
//
// kv is broadcast over j => softmax exactly uniform => attention out = v_row,
// independent of q (Wq unused):
//   attn_out[b,c] = sum_i vrow[b, i&63] * Wout[i,c],
//   vrow[b,:] = (LN(extra[b]) @ Wkv)[64:128].
// Per position: x = LN_C(cnn); h = x@W1; ff = (silu(h[512:])*h[:512])@W2;
//   out[b,c,p] = attn_out[b,c] + ff[p,c]
//
// Round-5: (1) FRAGMENT-TILED weight layout — each MFMA B-fragment (16 rows
// x 32 cols bf16 = 1KiB) stored contiguously, lane offset l15*64+lg*16, so
// every weight load is one coalesced 1KiB segment (previous layout was a
// 16-cache-line gather per load — the round-2..4 latency wall).
// (2) Raw barriers (lgkmcnt(0)+s_barrier, NO vmcnt drain) so weight loads
// stay in flight across barriers; val double-buffered in 2x8KiB chunks of
// 64 FFI — one barrier per chunk. LDS 48KiB -> 3 blocks/CU.
// ===========================================================================

#define BATCH 16
#define CDIM  256
#define HW    4096

using short8 = __attribute__((ext_vector_type(8))) short;
using f32x4  = __attribute__((ext_vector_type(4))) float;
using u32x2  = __attribute__((ext_vector_type(2))) unsigned int;
using u32x4  = __attribute__((ext_vector_type(4))) unsigned int;
typedef unsigned int   u32;
typedef unsigned short u16;

__device__ __forceinline__ u16 f2bf(float f) {
    u32 u = __float_as_uint(f);
    u += 0x7fffu + ((u >> 16) & 1u);   // round-nearest-even
    return (u16)(u >> 16);
}

__device__ __forceinline__ u32 cvtpk_bf16(float lo, float hi) {
    u32 r;
    asm("v_cvt_pk_bf16_f32 %0, %1, %2" : "=v"(r) : "v"(lo), "v"(hi));
    return r;
}

// lgkm drain (LDS visibility) + barrier, but NO vmcnt drain: global weight
// loads stay in flight across the barrier. "memory" pins compile-time order.
#define BAR() asm volatile("s_waitcnt lgkmcnt(0)\n\ts_barrier" ::: "memory")

// ---------------------------------------------------------------------------
// Fragment-tiled weight index: element (row n, col cc) of the bf16 transposed
// weight (rows = MFMA B-rows, cols = K) lives at
//   (n>>4)*(Rr*16) + (cc>>5)*512 + (n&15)*32 + (cc&31)
// where Rr = K-dim size. Each (n-tile, k-tile) fragment = 512 u16 = 1KiB
// contiguous; in-kernel lane offset = l15*32 + lg*8 (u16).
// ---------------------------------------------------------------------------

// ---------------------------------------------------------------------------
// Prep: blocks 0..15  -> collapsed attention rows (16 x 256 f32)
//       blocks 16..79 -> W1 (256x1024) -> w1t frag-tiled (Rr=256)
//       blocks 80..111-> W2 (512x256)  -> w2t frag-tiled (Rr=512)
// ---------------------------------------------------------------------------
__global__ void prep_kernel(const float* __restrict__ extra,
                            const float* __restrict__ ln2_g,
                            const float* __restrict__ ln2_b,
                            const float* __restrict__ Wkv,
                            const float* __restrict__ Wout,
                            const float* __restrict__ W1,
                            const float* __restrict__ W2,
                            float* __restrict__ attn_out,
                            u16* __restrict__ w1t,
                            u16* __restrict__ w2t)
{
    const int t = threadIdx.x;
    if (blockIdx.x < BATCH) {
        __shared__ float e[512];
        __shared__ float red[256], red2[256];
        __shared__ float vpart[256];
        __shared__ float vrow[64];
        const int b = blockIdx.x;
        float a0 = extra[b * 512 + t];
        float a1 = extra[b * 512 + 256 + t];
        e[t] = a0; e[t + 256] = a1;
        red[t] = a0 + a1; red2[t] = a0 * a0 + a1 * a1;
        __syncthreads();
        for (int off = 128; off; off >>= 1) {
            if (t < off) { red[t] += red[t + off]; red2[t] += red2[t + off]; }
            __syncthreads();
        }
        const float mean = red[0] * (1.0f / 512.0f);
        const float var  = red2[0] * (1.0f / 512.0f) - mean * mean;
        const float rs   = rsqrtf(var + 1e-5f);
        e[t]       = (e[t]       - mean) * rs * ln2_g[t]       + ln2_b[t];
        e[t + 256] = (e[t + 256] - mean) * rs * ln2_g[t + 256] + ln2_b[t + 256];
        __syncthreads();
        {   // vrow[d] = sum_i e[i]*Wkv[i,64+d], split over 4 i-parts
            const int d = t & 63, part = t >> 6;
            float acc = 0.0f;
            for (int i = part * 128; i < part * 128 + 128; ++i)
                acc += e[i] * Wkv[i * 128 + 64 + d];
            vpart[t] = acc;
        }
        __syncthreads();
        if (t < 64) vrow[t] = vpart[t] + vpart[t + 64] + vpart[t + 128] + vpart[t + 192];
        __syncthreads();
        {   // 4-way ILP on the dependent FMA chain
            float a0_ = 0.f, a1_ = 0.f, a2_ = 0.f, a3_ = 0.f;
            for (int i = 0; i < 512; i += 4) {
                a0_ += vrow[i & 63]       * Wout[(i)     * 256 + t];
                a1_ += vrow[(i + 1) & 63] * Wout[(i + 1) * 256 + t];
                a2_ += vrow[(i + 2) & 63] * Wout[(i + 2) * 256 + t];
                a3_ += vrow[(i + 3) & 63] * Wout[(i + 3) * 256 + t];
            }
            attn_out[b * 256 + t] = (a0_ + a1_) + (a2_ + a3_);
        }
    } else {
        __shared__ float tile[64][65];   // +1 pad: conflict-free transposed read
        int id = blockIdx.x - BATCH;
        const float* src; u16* dst; int Rr, Cc, tr, tc;
        if (id < 64) { src = W1; dst = w1t; Rr = 256; Cc = 1024; tr = id >> 4; tc = id & 15; }
        else { id -= 64; src = W2; dst = w2t; Rr = 512; Cc = 256; tr = id >> 2; tc = id & 3; }
        const int rl = t >> 6, col = t & 63;
#pragma unroll
        for (int i = 0; i < 16; ++i) {
            int r = i * 4 + rl;
            tile[r][col] = src[(size_t)(tr * 64 + r) * Cc + tc * 64 + col];
        }
        __syncthreads();
        // write frag-tiled: n = tc*64+n_local (dst row), cc = tr*64+c_local (K)
        const int n_local = t & 63, cgrp = t >> 6;
        const int n = tc * 64 + n_local;
        const int rowmul = Rr * 16;
#pragma unroll
        for (int run = 0; run < 2; ++run) {
            int cl0 = cgrp * 16 + run * 8;
            int cc0 = tr * 64 + cl0;
            short8 w;
#pragma unroll
            for (int e2 = 0; e2 < 8; ++e2)
                w[e2] = (short)f2bf(tile[cl0 + e2][n_local]);
            size_t idx = (size_t)(n >> 4) * rowmul + (size_t)(cc0 >> 5) * 512
                       + (n & 15) * 32 + (cc0 & 31);
            *(short8*)(dst + idx) = w;   // contiguous 16B, coalesced
        }
    }
}

// ---------------------------------------------------------------------------
// Main: 64 positions per block (1024 blocks), 4 waves, 3 blocks/CU.
// LDS: xs 64x256 bf16 (32 KiB), val[2] 64x64 bf16 (2x8 KiB, red overlaid).
// LDS swizzle: 16B-chunk phys = logicalChunk ^ (row & 7).
// Main loop: 8 chunks of 64 FFI; per chunk one raw barrier.
// ---------------------------------------------------------------------------
__global__ void __launch_bounds__(256) main_kernel(
    const float* __restrict__ cnn,      // (16,256,64,64)
    const float* __restrict__ ln1_g,
    const float* __restrict__ ln1_b,
    const u16*  __restrict__ w1t,       // frag-tiled (Rr=256)
    const u16*  __restrict__ w2t,       // frag-tiled (Rr=512)
    const float* __restrict__ attn_out, // (16,256)
    float* __restrict__ out)            // (16,256,64,64)
{
    __shared__ u16 xs[64 * 256];     // 32 KiB
    __shared__ u16 val[2][64 * 64];  // 2 x 8 KiB (val[0] head doubles as red[])
    float* red = (float*)val;

    const int t  = threadIdx.x;
    const int b  = blockIdx.x >> 6;
    const int p0 = (blockIdx.x & 63) << 6;
    const int p  = t & 63;
    const int q  = t >> 6;          // wave id
    const int l15 = p & 15;
    const int lg  = p >> 4;
    const int wlane = l15 * 32 + lg * 8;   // u16 offset inside a 1KiB fragment

    // ---- load cnn (coalesced along p) + LN stats ----
    const float* cb = cnn + (size_t)b * CDIM * HW + p0 + p;
    float v[64];
    float s = 0.0f, s2 = 0.0f;
#pragma unroll
    for (int i = 0; i < 64; ++i) {
        float x = cb[(size_t)(q * 64 + i) * HW];
        v[i] = x; s += x; s2 += x * x;
    }
    red[q * 64 + p] = s;
    red[256 + q * 64 + p] = s2;
    BAR();
    if (t < 64) {
        float ss = red[t] + red[64 + t] + red[128 + t] + red[192 + t];
        float sq = red[256 + t] + red[320 + t] + red[384 + t] + red[448 + t];
        float mean = ss * (1.0f / 256.0f);
        float var  = sq * (1.0f / 256.0f) - mean * mean;
        red[512 + t] = mean;
        red[576 + t] = rsqrtf(var + 1e-5f);
    }
    BAR();
    {   // normalize + bf16 pack + XOR-swizzled b128 LDS writes
        const float mean = red[512 + p], rs = red[576 + p];
#pragma unroll
        for (int ic = 0; ic < 8; ++ic) {
            u32x4 w;
#pragma unroll
            for (int e2 = 0; e2 < 4; ++e2) {
                int c = q * 64 + ic * 8 + e2 * 2;
                float x0 = (v[ic * 8 + e2 * 2]     - mean) * rs * ln1_g[c]     + ln1_b[c];
                float x1 = (v[ic * 8 + e2 * 2 + 1] - mean) * rs * ln1_g[c + 1] + ln1_b[c + 1];
                w[e2] = cvtpk_bf16(x0, x1);
            }
            int phys = (q * 8 + ic) ^ (p & 7);
            *(u32x4*)((char*)xs + p * 512 + phys * 16) = w;
        }
    }
    BAR();   // xs ready; all red reads done (val[0] now writable)

    f32x4 acc2[4][4];
#pragma unroll
    for (int n = 0; n < 4; ++n)
#pragma unroll
        for (int m = 0; m < 4; ++m)
            acc2[n][m] = (f32x4){0.0f, 0.0f, 0.0f, 0.0f};

    u32 pk[4][2];   // packed silu output: [m][pair] — 16 FFI values / lane

    // GEMM1(chunk): wave q owns FFI [c*64+q*16, +16) (xh) and +512 (gate).
    // Swapped operands: D col(l15)=position tile m, D rows(lg*4+j)=FFI.
#define GEMM1(c_) do {                                                           \
        const int r16x = (c_) * 4 + q;                                           \
        const int r16g = 32 + (c_) * 4 + q;                                      \
        f32x4 axh[4], ag[4];                                                     \
        _Pragma("unroll")                                                        \
        for (int m = 0; m < 4; ++m) {                                            \
            axh[m] = (f32x4){0.0f, 0.0f, 0.0f, 0.0f};                            \
            ag[m]  = (f32x4){0.0f, 0.0f, 0.0f, 0.0f};                            \
        }                                                                        \
        _Pragma("unroll")                                                        \
        for (int ks = 0; ks < 8; ++ks) {                                         \
            short8 a_[4];                                                        \
            _Pragma("unroll")                                                    \
            for (int m = 0; m < 4; ++m) {                                        \
                int row = m * 16 + l15;                                          \
                int ph  = (ks * 4 + lg) ^ (row & 7);                             \
                a_[m] = *(const short8*)((const char*)xs + row * 512 + ph * 16); \
            }                                                                    \
            short8 bx = *(const short8*)(w1t + (size_t)(r16x * 8 + ks) * 512 + wlane); \
            short8 bg = *(const short8*)(w1t + (size_t)(r16g * 8 + ks) * 512 + wlane); \
            _Pragma("unroll")                                                    \
            for (int m = 0; m < 4; ++m) {                                        \
                axh[m] = __builtin_amdgcn_mfma_f32_16x16x32_bf16(bx, a_[m], axh[m], 0, 0, 0); \
                ag[m]  = __builtin_amdgcn_mfma_f32_16x16x32_bf16(bg, a_[m], ag[m], 0, 0, 0);  \
            }                                                                    \
        }                                                                        \
        _Pragma("unroll")                                                        \
        for (int m = 0; m < 4; ++m) {                                            \
            float sv[4];                                                         \
            _Pragma("unroll")                                                    \
            for (int j = 0; j < 4; ++j) {                                        \
                float g = ag[m][j];                                              \
                sv[j] = axh[m][j] * g * __builtin_amdgcn_rcpf(1.0f + __expf(-g)); \
            }                                                                    \
            pk[m][0] = cvtpk_bf16(sv[0], sv[1]);                                 \
            pk[m][1] = cvtpk_bf16(sv[2], sv[3]);                                 \
        }                                                                        \
    } while (0)

    // conflict-free 8B val writes: row=position, FFI-local col = q*16+lg*4
#define VALWRITE(dst_) do {                                                      \
        _Pragma("unroll")                                                        \
        for (int m = 0; m < 4; ++m) {                                            \
            int row = m * 16 + l15;                                              \
            int ph  = (q * 2 + (lg >> 1)) ^ (row & 7);                           \
            *(u32x2*)((char*)(dst_) + row * 128 + ph * 16 + (lg & 1) * 8) =      \
                (u32x2){pk[m][0], pk[m][1]};                                     \
        }                                                                        \
    } while (0)

    // GEMM2(chunk): wave q owns out-channels [q*64, +64); K = 64 FFI of chunk
#define GEMM2(c_, src_) do {                                                     \
        _Pragma("unroll")                                                        \
        for (int ks = 0; ks < 2; ++ks) {                                         \
            short8 a2[4], b2[4];                                                 \
            _Pragma("unroll")                                                    \
            for (int m = 0; m < 4; ++m) {                                        \
                int row = m * 16 + l15;                                          \
                int ph  = (ks * 4 + lg) ^ (row & 7);                             \
                a2[m] = *(const short8*)((const char*)(src_) + row * 128 + ph * 16); \
            }                                                                    \
            _Pragma("unroll")                                                    \
            for (int n = 0; n < 4; ++n)                                          \
                b2[n] = *(const short8*)(w2t + (size_t)((q * 4 + n) * 16 + (c_) * 2 + ks) * 512 + wlane); \
            _Pragma("unroll")                                                    \
            for (int n = 0; n < 4; ++n)                                          \
            _Pragma("unroll")                                                    \
            for (int m = 0; m < 4; ++m)                                          \
                acc2[n][m] = __builtin_amdgcn_mfma_f32_16x16x32_bf16(a2[m], b2[n], acc2[n][m], 0, 0, 0); \
        }                                                                        \
    } while (0)

    GEMM1(0);
    VALWRITE(val[0]);
    BAR();
#pragma unroll
    for (int c = 0; c < 8; ++c) {
        if (c < 7) GEMM1(c + 1);          // regs only; weight loads coalesced
        GEMM2(c, val[c & 1]);
        if (c < 7) {
            VALWRITE(val[(c + 1) & 1]);   // other buffer: readers done at last BAR
            BAR();
        }
    }

    // ---- epilogue: + attn row, f32x4 stores (4 consecutive positions) ----
    float att[4];
#pragma unroll
    for (int n = 0; n < 4; ++n) att[n] = attn_out[b * 256 + q * 64 + n * 16 + l15];
    float* ob = out + (size_t)b * CDIM * HW;
#pragma unroll
    for (int n = 0; n < 4; ++n) {
        int c = q * 64 + n * 16 + l15;
#pragma unroll
        for (int m = 0; m < 4; ++m) {
            f32x4 r = acc2[n][m];
            r[0] += att[n]; r[1] += att[n]; r[2] += att[n]; r[3] += att[n];
            *(f32x4*)(ob + (size_t)c * HW + p0 + m * 16 + lg * 4) = r;
        }
    }
#undef GEMM1
#undef GEMM2
#undef VALWRITE
}

// ---------------------------------------------------------------------------
extern "C" void kernel_launch(void* const* d_in, const int* in_sizes, int n_in,
                              void* d_out, int out_size, void* d_ws, size_t ws_size,
                              hipStream_t stream) {
    const float* cnn   = (const float*)d_in[0];
    const float* extra = (const float*)d_in[1];
    const float* ln1_g = (const float*)d_in[2];
    const float* ln1_b = (const float*)d_in[3];
    const float* ln2_g = (const float*)d_in[4];
    const float* ln2_b = (const float*)d_in[5];
    // d_in[6] = Wq — provably unused
    const float* Wkv   = (const float*)d_in[7];
    const float* Wout  = (const float*)d_in[8];
    const float* W1    = (const float*)d_in[9];
    const float* W2    = (const float*)d_in[10];
    float* out = (float*)d_out;

    char* ws = (char*)d_ws;
    float* attn_out = (float*)ws;                          // 16 KiB
    u16*   w1t      = (u16*)(ws + 16 * 1024);              // 512 KiB
    u16*   w2t      = (u16*)(ws + 16 * 1024 + 512 * 1024); // 256 KiB

    prep_kernel<<<112, 256, 0, stream>>>(extra, ln2_g, ln2_b, Wkv, Wout, W1, W2,
                                         attn_out, w1t, w2t);
    main_kernel<<<BATCH * 64, 256, 0, stream>>>(cnn, ln1_g, ln1_b, w1t, w2t,
                                                attn_out, out);
}